// Round 14
// baseline (1646.678 us; speedup 1.0000x reference)
//
#include <hip/hip_runtime.h>

// Tree-GRU encoder, round 14: B-weights in REGISTERS + x/h wave specialization.
//  - R13 diagnosis: per-CU LDS port (12cy/ds_read, serialized over 8 waves) was
//    ~40% of wall; 96 of 128 reads/chunk were B-weights identical across waves.
//  - Fix: each wave holds its full K=512 B-panel (3 gates x 16 ksteps) in 192
//    VGPRs, preloaded once per kernel from wt (rotated-chunk order -> compile-
//    time register indices). No LDS weight region at all.
//  - Both matrices (Wx+Uh) = 384 VGPR don't fit -> wave specialization: waves
//    pair up as (x-wave, h-wave) per 16-row group; x-wave computes x-side gate
//    accs, h-wave h-side; exchange via 12KB LDS slab once per tile (fragments
//    are positionally identical -> flat per-lane slots).
//  - LDS: Xb dbuf 2x8K | Hb dbuf 2x8K | XACC 12K = 45KB. Tile 64 rows x 16 cols.
//  - Carried from R13: dataflow flags, no acquire fence, nt zero-fill, rotated
//    chunk order ending at own column chunk (hprev from LDS), sc0sc1 stores for
//    single-writer buffers, atomic only for children-sum, T14 load-before-store.

#define NL 256
#define NB 128
#define NH 512
#define NG (NB * NL)

typedef short short8 __attribute__((ext_vector_type(8)));
typedef float f32x4 __attribute__((ext_vector_type(4)));

__device__ __forceinline__ float bf2f(unsigned short u) {
  union { unsigned int i; float f; } c; c.i = ((unsigned int)u) << 16; return c.f;
}
__device__ __forceinline__ unsigned short f2bf(float f) {
  union { float f; unsigned int i; } c; c.f = f;
  return (unsigned short)((c.i + 0x7FFFu + ((c.i >> 16) & 1u)) >> 16);  // RNE
}
__device__ __forceinline__ short8 pk_bf16(f32x4 a, f32x4 b) {
  union { unsigned int u[4]; short8 s; } r;
  asm("v_cvt_pk_bf16_f32 %0, %1, %2" : "=v"(r.u[0]) : "v"(a[0]), "v"(a[1]));
  asm("v_cvt_pk_bf16_f32 %0, %1, %2" : "=v"(r.u[1]) : "v"(a[2]), "v"(a[3]));
  asm("v_cvt_pk_bf16_f32 %0, %1, %2" : "=v"(r.u[2]) : "v"(b[0]), "v"(b[1]));
  asm("v_cvt_pk_bf16_f32 %0, %1, %2" : "=v"(r.u[3]) : "v"(b[2]), "v"(b[3]));
  return r.s;
}
__device__ __forceinline__ void atom_pk_bf16(unsigned short* p, unsigned int ud) {
  asm volatile("global_atomic_pk_add_bf16 %0, %1, off" :: "v"((void*)p), "v"(ud) : "memory");
}
__device__ __forceinline__ void store_u32_wt(unsigned short* p, unsigned int v) {
  asm volatile("global_store_dword %0, %1, off sc0 sc1" :: "v"((void*)p), "v"(v) : "memory");
}

__device__ __forceinline__ void level_wait(unsigned int* c, unsigned int target) {
  if (threadIdx.x == 0) {
    while (__hip_atomic_load(c, __ATOMIC_RELAXED, __HIP_MEMORY_SCOPE_AGENT) < target)
      __builtin_amdgcn_s_sleep(2);
  }
  __syncthreads();
}

// ---- prep: zero state buffers with write-through no-allocate stores ----
__global__ void prep_zero(f32x4* __restrict__ base, int n16) {
  const f32x4 z = {0.f, 0.f, 0.f, 0.f};
  int i = blockIdx.x * blockDim.x + threadIdx.x;
  int stride = gridDim.x * blockDim.x;
  for (int j = i; j < n16; j += stride) {
    asm volatile("global_store_dwordx4 %0, %1, off sc0 sc1 nt"
                 :: "v"((void*)(base + j)), "v"(z) : "memory");
  }
}

// ---- prep: 4 weight matrices [512][1536] f32 -> transposed [1536][512] bf16 ----
__global__ void prep_wt4(const float* __restrict__ w0, const float* __restrict__ w1,
                         const float* __restrict__ w2, const float* __restrict__ w3,
                         unsigned short* __restrict__ wt) {
  __shared__ float t[32][33];
  const float* w = blockIdx.z == 0 ? w0 : blockIdx.z == 1 ? w1 : blockIdx.z == 2 ? w2 : w3;
  unsigned short* dst = wt + (size_t)blockIdx.z * 1536 * 512;
  int n0 = blockIdx.x * 32, k0 = blockIdx.y * 32;
  int tx = threadIdx.x & 31, ty = threadIdx.x >> 5;
  #pragma unroll
  for (int i = 0; i < 4; ++i)
    t[ty + 8 * i][tx] = w[(size_t)(k0 + ty + 8 * i) * 1536 + n0 + tx];
  __syncthreads();
  #pragma unroll
  for (int i = 0; i < 4; ++i)
    dst[(size_t)(n0 + ty + 8 * i) * 512 + k0 + tx] = f2bf(t[tx][ty + 8 * i]);
}

// ---- prep: depths, level buckets, slots, parent slots (1 block, 256 thr) ----
__global__ void prep_sched(const int* __restrict__ td_pidx,
                           const float* __restrict__ td_pval,
                           int* __restrict__ sched, int* __restrict__ meta,
                           int* __restrict__ gidx, int* __restrict__ pslot) {
  __shared__ unsigned char dep[NB][NL];
  __shared__ unsigned short cnb[NB][256];
  __shared__ int cnt[256];
  __shared__ int off[257];
  __shared__ int dmax_s;
  const int tid = threadIdx.x;
  for (int j = tid; j < NB * 256; j += 256) ((unsigned short*)cnb)[j] = 0;
  if (tid == 0) dmax_s = 0;
  __syncthreads();
  if (tid < NB) {
    int b = tid, lmax = 0;
    for (int i = 0; i < NL; ++i) {
      float pv = td_pval[i * NB + b];
      int pi = td_pidx[i * NB + b];
      int d = (pv != 0.f) ? (int)dep[b][pi] + 1 : 0;   // head[i] < i
      dep[b][i] = (unsigned char)d;
      cnb[b][d]++;
      lmax = max(lmax, d);
    }
    atomicMax(&dmax_s, lmax);
  }
  __syncthreads();
  {
    int s = 0;
    for (int b = 0; b < NB; ++b) s += cnb[b][tid];
    cnt[tid] = s;
  }
  __syncthreads();
  if (tid == 0) {
    int s = 0;
    for (int d = 0; d < 256; ++d) { off[d] = s; s += cnt[d]; }
    off[256] = s;
  }
  __syncthreads();
  {
    int run = off[tid];
    for (int b = 0; b < NB; ++b) {
      int t = cnb[b][tid];
      cnb[b][tid] = (unsigned short)run;
      run += t;
    }
  }
  __syncthreads();
  if (tid < NB) {
    int b = tid;
    for (int i = 0; i < NL; ++i) {
      float pv = td_pval[i * NB + b];
      int pi = td_pidx[i * NB + b];
      int d = dep[b][i];
      int g = cnb[b][d]++;
      sched[g] = (b << 8) | i;
      gidx[b * NL + i] = g;
      pslot[g] = (pv != 0.f) ? gidx[b * NL + pi] : -1;
    }
  }
  if (tid == 0) meta[0] = dmax_s;
  __syncthreads();
  meta[1 + tid] = off[tid];
  meta[257 + tid] = cnt[tid];
}

// ---- prep: gather emb rows into slot order, f32 -> bf16 ----
__global__ void prep_xc(const float* __restrict__ emb, const int* __restrict__ sched,
                        unsigned short* __restrict__ Xc) {
  int g = blockIdx.x * 4 + (threadIdx.x >> 6);
  int lane = threadIdx.x & 63;
  int e = sched[g];
  int b = e >> 8, node = e & 255;
  const float* src = emb + ((size_t)node * NB + b) * 512 + lane * 8;
  f32x4 v0 = *(const f32x4*)src;
  f32x4 v1 = *(const f32x4*)(src + 4);
  *(short8*)(Xc + (size_t)g * 512 + lane * 8) = pk_bf16(v0, v1);
}

// staging reg<->LDS helpers (compile-time register indices; addresses runtime)
#define LDJ2(j, s)                                                 \
  { const int c_ = (ck + 1 + (j)) & 7;                             \
    s[0] = *(const short8*)(sp + c_ * 64);                         \
    s[1] = *(const short8*)(sp + c_ * 64 + 8); }
#define WRB2(buf, s)                                               \
  { *(short8*)((buf) + srow * 128 + sw0) = s[0];                   \
    *(short8*)((buf) + srow * 128 + sw1) = s[1]; }

// ---- main fused kernel, flag-synced, wave-specialized ----
// grid = 256 x 512 thr (8 waves, 1 block/CU). bi = cg*8 + pass*4 + rep.
// Wave w: role = w&1 (0 = x-side, 1 = h-side), rowgroup rg = w>>1 (16 rows).
// Block tile: 64 rows x 16 cols. B-panel (3 gates x K512) lives in 192 VGPRs.
// LDS: Xb0 8K | Xb1 8K | Hb0 8K | Hb1 8K | XACC 12K = 45056 B.
__launch_bounds__(512, 2)
__global__ void tree_gru(const float* __restrict__ dt_b,
                         const float* __restrict__ td_b,
                         const unsigned short* __restrict__ wt,
                         const unsigned short* __restrict__ Xc,
                         unsigned short* __restrict__ Hdt,
                         unsigned short* __restrict__ Htd,
                         unsigned short* __restrict__ Hfd,
                         const unsigned short* __restrict__ zrow,
                         const int* __restrict__ meta,
                         const int* __restrict__ pslot,
                         unsigned int* __restrict__ ctr,
                         const int* __restrict__ sched,
                         const int* __restrict__ root_index,
                         float* __restrict__ out) {
  extern __shared__ unsigned char lds[];
  unsigned char* Xb0 = lds;
  unsigned char* Xb1 = lds + 8192;
  unsigned char* Hb0 = lds + 16384;
  unsigned char* Hb1 = lds + 24576;
  float* XACC = (float*)(lds + 32768);        // 4 pairs x 64 lanes x 12 f32

  const int tid = threadIdx.x;
  const int bi  = blockIdx.x;
  const int cg   = bi >> 3;          // 0..31 col group (16 cols)
  const int pass = (bi >> 2) & 1;    // 0 = DT bottom-up, 1 = TD top-down
  const int rep  = bi & 3;           // row-tile replica
  const int w  = tid >> 6, l = tid & 63;
  const int role = w & 1;            // 0 = x-wave, 1 = h-wave
  const int rg   = w >> 1;           // rowgroup (16 rows)
  const int lm = l & 15, kg = l >> 4;
  const int col = cg * 16 + lm;
  const int ck = cg >> 2;            // k-chunk containing this block's columns

  // ---- B-panel preload into registers (rotated chunk order -> static idx) ----
  const unsigned short* wtm = wt + (size_t)(pass * 2 + role) * (1536 * 512);
  short8 B[48];
  #pragma unroll
  for (int ci = 0; ci < 8; ++ci) {
    const int cc = (ck + 1 + ci) & 7;
    #pragma unroll
    for (int ks = 0; ks < 2; ++ks)
      #pragma unroll
      for (int g3 = 0; g3 < 3; ++g3)
        B[(ci * 2 + ks) * 3 + g3] = *(const short8*)(
            wtm + (size_t)(g3 * 512 + cg * 16 + lm) * 512 + cc * 64 + ks * 32 + kg * 8);
  }

  const float* bias = pass ? td_b : dt_b;
  const float br = bias[col], bz = bias[NH + col], bn = bias[2 * NH + col];
  // staging: role's 256 threads cover 64 rows x 4 quarter-slots (2x16B each)
  const int rtid = rg * 64 + l;
  const int srow = rtid >> 2, sq = rtid & 3;
  const int sw0 = ((sq * 2)     ^ (srow & 7)) << 4;
  const int sw1 = ((sq * 2 + 1) ^ (srow & 7)) << 4;
  unsigned char* Sb0 = role ? Hb0 : Xb0;       // own staging buffers
  unsigned char* Sb1 = role ? Hb1 : Xb1;
  const unsigned char* Ar0 = role ? Hb0 : Xb0; // own read buffers
  const unsigned char* Ar1 = role ? Hb1 : Xb1;
  const int arow = (rg * 16 + lm) * 128;       // (row&7) == (lm&7)
  const int rsw = (lm & 7) << 4;
  const int ccw = 2 * ((cg & 3) * 16 + lm);    // col's byte offset within chunk row
  const int ccslot = ccw >> 4, ccin = ccw & 15;
  const int Dmax = meta[0];
  unsigned int* doneP = ctr + pass * 256;

  for (int p = 0; p <= Dmax; ++p) {
    const int d = pass ? p : (Dmax - p);
    const int off_d = meta[1 + d];
    const int cnt_d = meta[257 + d];
    const int T = (cnt_d + 63) >> 6;
    if (T <= rep) continue;                    // no tiles -> no wait
    const int dl = pass ? d - 1 : d + 1;       // dependency level
    if (dl >= 0 && dl <= Dmax)
      level_wait(doneP + dl, (unsigned int)meta[257 + dl] * 32u);

    unsigned int myrows = 0;
    // first tile staging pointer + preload chunks 0,1
    const unsigned short* sp;
    {
      const int gg = off_d + min(rep * 64 + srow, cnt_d - 1);
      if (role == 0) sp = Xc + (size_t)gg * 512 + sq * 16;
      else if (pass == 0) sp = Hdt + (size_t)gg * 512 + sq * 16;
      else { int ps = pslot[gg]; sp = (ps >= 0 ? Htd + (size_t)ps * 512 : zrow) + sq * 16; }
    }
    short8 s0[2], s1[2];
    LDJ2(0, s0);
    LDJ2(1, s1);

    for (int t = rep; t < T; t += 4) {
      const int g0 = off_d + t * 64;
      const int rows = min(64, cnt_d - t * 64);
      __syncthreads();                         // prior tile fully consumed
      WRB2(Sb0, s0);                           // chunk j=0 -> buf0
      LDJ2(2, s0);
      __syncthreads();                         // buf0 visible

      f32x4 a0 = {0,0,0,0}, a1 = {0,0,0,0}, a2 = {0,0,0,0};   // r,z,n gate accs
      #pragma unroll
      for (int ci = 0; ci < 8; ++ci) {
        const unsigned char* Ar = (ci & 1) ? Ar1 : Ar0;
        #pragma unroll
        for (int ks = 0; ks < 2; ++ks) {
          const int so = (((ks << 2) | kg) ^ (lm & 7)) << 4;
          short8 a = *(const short8*)(Ar + arow + so);
          a0 = __builtin_amdgcn_mfma_f32_16x16x32_bf16(a, B[(ci * 2 + ks) * 3 + 0], a0, 0, 0, 0);
          a1 = __builtin_amdgcn_mfma_f32_16x16x32_bf16(a, B[(ci * 2 + ks) * 3 + 1], a1, 0, 0, 0);
          a2 = __builtin_amdgcn_mfma_f32_16x16x32_bf16(a, B[(ci * 2 + ks) * 3 + 2], a2, 0, 0, 0);
        }
        if (ci < 7) {
          unsigned char* Wb = (ci & 1) ? Sb0 : Sb1;
          if ((ci & 1) == 0) { WRB2(Wb, s1); if (ci < 5) LDJ2(ci + 3, s1); }
          else               { WRB2(Wb, s0); if (ci < 5) LDJ2(ci + 3, s0); }
          __syncthreads();
        }
      }
      // x-waves publish gate accs (fragments positionally identical to h-wave)
      if (role == 0) {
        float* pb = XACC + (size_t)(rg * 64 + l) * 12;
        *(f32x4*)(pb + 0) = a0; *(f32x4*)(pb + 4) = a1; *(f32x4*)(pb + 8) = a2;
      }
      __syncthreads();
      // h-waves: combine, GRU math (values only)
      float hv[4];
      if (role == 1) {
        const float* pb = XACC + (size_t)(rg * 64 + l) * 12;
        f32x4 xR = *(const f32x4*)(pb + 0);
        f32x4 xZ = *(const f32x4*)(pb + 4);
        f32x4 xN = *(const f32x4*)(pb + 8);
        #pragma unroll
        for (int q = 0; q < 4; ++q) {
          const int r = rg * 16 + kg * 4 + q;
          const float hprev = bf2f(*(const unsigned short*)(
              Hb1 + r * 128 + (((ccslot ^ (r & 7)) << 4) | ccin)));
          float rr = 1.f / (1.f + __expf(-(xR[q] + br + a0[q])));
          float zz = 1.f / (1.f + __expf(-(xZ[q] + bz + a1[q])));
          float e2 = __expf(2.f * (xN[q] + bn + rr * a2[q]));
          float nn = (e2 - 1.f) / (e2 + 1.f);  // tanh
          hv[q] = (1.f - zz) * nn + zz * hprev;
        }
      }
      // T14: next tile's staging loads issued before h-wave stores
      if (t + 4 < T) {
        const int gg = off_d + min((t + 4) * 64 + srow, cnt_d - 1);
        if (role == 0) sp = Xc + (size_t)gg * 512 + sq * 16;
        else if (pass == 0) sp = Hdt + (size_t)gg * 512 + sq * 16;
        else { int ps = pslot[gg]; sp = (ps >= 0 ? Htd + (size_t)ps * 512 : zrow) + sq * 16; }
        LDJ2(0, s0);
        LDJ2(1, s1);
      }
      // h-waves: stores (lanes lm, lm^1 share row -> pair-uniform predicate)
      if (role == 1) {
        #pragma unroll
        for (int q = 0; q < 4; ++q) {
          const int r = rg * 16 + kg * 4 + q;
          float ho = __shfl_xor(hv[q], 1);
          if (r < rows && !(lm & 1)) {
            const int g = g0 + r;
            unsigned int ud;
            asm("v_cvt_pk_bf16_f32 %0, %1, %2" : "=v"(ud) : "v"(hv[q]), "v"(ho));
            if (pass == 0) {
              store_u32_wt(Hfd + (size_t)g * 512 + col, ud);   // single writer
              int ps = pslot[g];
              if (ps >= 0) atom_pk_bf16(Hdt + (size_t)ps * 512 + col, ud);
            } else {
              store_u32_wt(Htd + (size_t)g * 512 + col, ud);   // single writer
            }
          }
        }
      }
      myrows += (unsigned int)rows;
    }
    // level commit: drain this level's stores once, then count
    asm volatile("s_waitcnt vmcnt(0)" ::: "memory");
    __syncthreads();
    if (tid == 0) {
      __hip_atomic_fetch_add(doneP + d, myrows,
                             __ATOMIC_RELAXED, __HIP_MEMORY_SCOPE_AGENT);
      __hip_atomic_fetch_add(ctr + 512 + pass, myrows,
                             __ATOMIC_RELAXED, __HIP_MEMORY_SCOPE_AGENT);
    }
  }

  // tail finalize: wait both passes fully done, stream compact -> out (f32)
  level_wait(ctr + 512, (unsigned int)NG * 32u);
  level_wait(ctr + 513, (unsigned int)NG * 32u);
  #pragma unroll
  for (int it = 0; it < 4; ++it) {
    const int g = bi * 128 + it * 32 + (tid >> 4);
    const int part = tid & 15;
    const int e = sched[g];
    const int b = e >> 8, node = e & 255;
    float* dst = out + ((size_t)b * NL + node) * 1024;
    const bool isroot = (node == root_index[b]);
    float* dst2 = out + (size_t)NB * NL * 1024 + (size_t)b * 1024;
    const unsigned short* sA = Hfd + (size_t)g * 512 + part * 32;
    const unsigned short* sB = Htd + (size_t)g * 512 + part * 32;
    #pragma unroll
    for (int half = 0; half < 2; ++half) {
      const unsigned short* s = half ? sB : sA;
      const int o = half * 512 + part * 32;
      #pragma unroll
      for (int j = 0; j < 4; ++j) {
        short8 v = *(const short8*)(s + j * 8);
        f32x4 lo, hi;
        #pragma unroll
        for (int q = 0; q < 4; ++q) {
          lo[q] = bf2f((unsigned short)v[q]);
          hi[q] = bf2f((unsigned short)v[4 + q]);
        }
        __builtin_nontemporal_store(lo, (f32x4*)(dst + o + j * 8));
        __builtin_nontemporal_store(hi, (f32x4*)(dst + o + j * 8 + 4));
        if (isroot) {
          *(f32x4*)(dst2 + o + j * 8) = lo;
          *(f32x4*)(dst2 + o + j * 8 + 4) = hi;
        }
      }
    }
  }
}

extern "C" void kernel_launch(void* const* d_in, const int* in_sizes, int n_in,
                              void* d_out, int out_size, void* d_ws, size_t ws_size,
                              hipStream_t stream) {
  (void)in_sizes; (void)n_in; (void)out_size; (void)ws_size;
  const float* emb      = (const float*)d_in[0];
  const int*   td_pidx  = (const int*)d_in[4];
  const float* td_pval  = (const float*)d_in[5];
  const int*   root_idx = (const int*)d_in[6];
  const float* dt_Wx    = (const float*)d_in[7];
  const float* dt_Uh    = (const float*)d_in[8];
  const float* dt_b     = (const float*)d_in[9];
  const float* td_Wx    = (const float*)d_in[10];
  const float* td_Uh    = (const float*)d_in[11];
  const float* td_b     = (const float*)d_in[12];
  float* out = (float*)d_out;

  unsigned short* wt   = (unsigned short*)d_ws;
  unsigned short* Xc   = wt + (size_t)4 * 1536 * 512;
  unsigned short* Hdt  = Xc + (size_t)NG * NH;      // ---- zeroed region start
  unsigned short* Htd  = Hdt + (size_t)NG * NH;
  unsigned short* Hfd  = Htd + (size_t)NG * NH;
  unsigned short* zrow = Hfd + (size_t)NG * NH;
  unsigned int*   ctr  = (unsigned int*)(zrow + NH); // 520 u32 ---- zeroed end
  int* sched = (int*)(ctr + 520);
  int* meta  = sched + NG;
  int* gidx  = meta + 520;
  int* pslot = gidx + NG;

  // zero Hdt..ctr with write-through no-L2-allocate stores (16B units)
  const int n16 = (int)(((size_t)3 * NG * NH * 2 + NH * 2 + 520 * 4) / 16);
  prep_zero<<<dim3(2048), dim3(256), 0, stream>>>((f32x4*)Hdt, n16);
  prep_wt4<<<dim3(48, 16, 4), dim3(256), 0, stream>>>(dt_Wx, dt_Uh, td_Wx, td_Uh, wt);
  prep_sched<<<dim3(1), dim3(256), 0, stream>>>(td_pidx, td_pval, sched, meta, gidx, pslot);
  prep_xc<<<dim3(NG / 4), dim3(256), 0, stream>>>(emb, sched, Xc);

  (void)hipFuncSetAttribute((const void*)tree_gru,
                            hipFuncAttributeMaxDynamicSharedMemorySize, 45056);

  void* args[] = {
    (void*)&dt_b, (void*)&td_b, (void*)&wt, (void*)&Xc, (void*)&Hdt, (void*)&Htd,
    (void*)&Hfd, (void*)&zrow, (void*)&meta, (void*)&pslot, (void*)&ctr,
    (void*)&sched, (void*)&root_idx, (void*)&out
  };
  (void)hipLaunchCooperativeKernel((const void*)tree_gru, dim3(256), dim3(512),
                                   args, 45056u, stream);
}